// Round 4
// baseline (185.985 us; speedup 1.0000x reference)
//
#include <hip/hip_runtime.h>

// SparseLayer: out[n] = ((self[n] + sum_j neigh[n*32+j]) / 33) @ W + bias
// N=50000, NEIGH=32, D=128, fp32.
//
// Persistent-ish pipeline: 512 blocks (2/CU), each block owns ~3 tiles of 32
// nodes. Per tile-iteration the 32-step GEMM of tile t is FUSED with the
// 32-row aggregation of tile t+1, so the CU's HBM demand never pauses during
// the LDS/VALU GEMM phase (which was ~17% idle time in the serial version).
// agg rows are wave-private -> no barriers after the one-time W staging.

typedef float f32x4 __attribute__((ext_vector_type(4)));

constexpr int D       = 128;
constexpr int D4      = D / 4;          // 32
constexpr int NEIGH   = 32;             // == D4: fused loop trip counts match
constexpr int WAVES   = 8;
constexpr int THREADS = WAVES * 64;     // 512
constexpr int NPW     = 4;              // nodes per wave
constexpr int NPB     = WAVES * NPW;    // 32 nodes per tile
constexpr int GRID    = 512;            // 2 blocks/CU on 256 CUs

__global__ __launch_bounds__(THREADS, 4)
void sparse_layer_pipe(const float* __restrict__ self_vecs,
                       const float* __restrict__ neigh_vecs,
                       const float* __restrict__ weight,
                       const float* __restrict__ bias,
                       float* __restrict__ out, int n_nodes)
{
    __shared__ float w_lds[D * D];        // 64 KiB
    __shared__ float agg_lds[NPB][D];     // 16 KiB (80 KiB total -> 2 blocks/CU)

    // ---- stage W into LDS (one-time; only barrier in the kernel) ----
    {
        const f32x4* w4 = reinterpret_cast<const f32x4*>(weight);
        f32x4*       wp = reinterpret_cast<f32x4*>(w_lds);
        #pragma unroll
        for (int i = 0; i < (D * D / 4) / THREADS; ++i)
            wp[threadIdx.x + i * THREADS] = w4[threadIdx.x + i * THREADS];
    }
    __syncthreads();

    const int wave = threadIdx.x >> 6;
    const int lane = threadIdx.x & 63;
    const int half = lane >> 5;           // 0/1
    const int c4   = lane & 31;           // float4 column

    const int lA = wave * NPW + half;     // wave-private agg rows
    const int lB = lA + 2;

    const f32x4* s4 = reinterpret_cast<const f32x4*>(self_vecs);
    const f32x4* g4 = reinterpret_cast<const f32x4*>(neigh_vecs);
    const f32x4* wl = reinterpret_cast<const f32x4*>(w_lds);
    f32x4* arA = reinterpret_cast<f32x4*>(agg_lds[lA]);
    f32x4* arB = reinterpret_cast<f32x4*>(agg_lds[lB]);
    const f32x4 bv = reinterpret_cast<const f32x4*>(bias)[c4];
    constexpr float inv = 1.0f / (NEIGH + 1);

    const int n_tiles = (n_nodes + NPB - 1) / NPB;    // 1563

    int t = blockIdx.x;
    if (t >= n_tiles) return;

    // ---- prologue: aggregate first tile ----
    {
        const long nA = (long)t * NPB + lA, nB = nA + 2;
        const bool vA = nA < n_nodes, vB = nB < n_nodes;
        f32x4 aA = (f32x4)0.0f, aB = (f32x4)0.0f;
        const f32x4* pA = g4 + nA * (long)NEIGH * D4 + c4;
        const f32x4* pB = g4 + nB * (long)NEIGH * D4 + c4;
        if (vB) {
            aA = __builtin_nontemporal_load(&s4[nA * D4 + c4]);
            aB = __builtin_nontemporal_load(&s4[nB * D4 + c4]);
            #pragma unroll 8
            for (int r = 0; r < NEIGH; ++r) {
                aA += __builtin_nontemporal_load(&pA[r * D4]);
                aB += __builtin_nontemporal_load(&pB[r * D4]);
            }
        } else if (vA) {
            aA = __builtin_nontemporal_load(&s4[nA * D4 + c4]);
            #pragma unroll 8
            for (int r = 0; r < NEIGH; ++r)
                aA += __builtin_nontemporal_load(&pA[r * D4]);
        }
        if (vA) arA[c4] = aA * inv;
        if (vB) arB[c4] = aB * inv;
    }

    // ---- main loop: GEMM(tile t) fused with aggregate(tile t+GRID) ----
    for (; t < n_tiles; t += GRID) {
        const int  tn  = t + GRID;
        const long mA  = (long)tn * NPB + lA, mB = mA + 2;
        const bool wAv = (tn < n_tiles) && (mA < n_nodes);
        const bool wBv = (tn < n_tiles) && (mB < n_nodes);
        const f32x4* qA = g4 + mA * (long)NEIGH * D4 + c4;
        const f32x4* qB = g4 + mB * (long)NEIGH * D4 + c4;
        f32x4 nxA = (f32x4)0.0f, nxB = (f32x4)0.0f;
        if (wAv) nxA = __builtin_nontemporal_load(&s4[mA * D4 + c4]);
        if (wBv) nxB = __builtin_nontemporal_load(&s4[mB * D4 + c4]);

        f32x4 oA = (f32x4)0.0f, oB = (f32x4)0.0f;

        #pragma unroll 4
        for (int k4 = 0; k4 < D4; ++k4) {
            // phase-1 slice of NEXT tile (keeps HBM busy through the GEMM)
            if (wBv) {
                nxA += __builtin_nontemporal_load(&qA[k4 * D4]);
                nxB += __builtin_nontemporal_load(&qB[k4 * D4]);
            } else if (wAv) {
                nxA += __builtin_nontemporal_load(&qA[k4 * D4]);
            }
            // phase-2 slice of CURRENT tile
            f32x4 a0 = arA[k4];                       // broadcast (free)
            f32x4 a1 = arB[k4];
            f32x4 w0 = wl[(4 * k4 + 0) * D4 + c4];    // conflict-free b128
            f32x4 w1 = wl[(4 * k4 + 1) * D4 + c4];
            f32x4 w2 = wl[(4 * k4 + 2) * D4 + c4];
            f32x4 w3 = wl[(4 * k4 + 3) * D4 + c4];
            oA += a0.x * w0;  oA += a0.y * w1;  oA += a0.z * w2;  oA += a0.w * w3;
            oB += a1.x * w0;  oB += a1.y * w1;  oB += a1.z * w2;  oB += a1.w * w3;
        }

        // write out(t)
        const long nA = (long)t * NPB + lA, nB = nA + 2;
        if (nA < n_nodes) reinterpret_cast<f32x4*>(out)[nA * D4 + c4] = oA + bv;
        if (nB < n_nodes) reinterpret_cast<f32x4*>(out)[nB * D4 + c4] = oB + bv;

        // publish agg(t+GRID) — program-ordered after all agg(t) reads, same wave
        if (wAv) arA[c4] = nxA * inv;
        if (wBv) arB[c4] = nxB * inv;
    }
}

extern "C" void kernel_launch(void* const* d_in, const int* in_sizes, int n_in,
                              void* d_out, int out_size, void* d_ws, size_t ws_size,
                              hipStream_t stream) {
    const float* self_vecs  = (const float*)d_in[0];
    const float* neigh_vecs = (const float*)d_in[1];
    // d_in[2] = neigh_num (==32, compile-time NEIGH)
    const float* weight     = (const float*)d_in[3];
    const float* bias       = (const float*)d_in[4];
    float*       out        = (float*)d_out;

    const int n_nodes = in_sizes[0] / D;                 // 50000
    const int n_tiles = (n_nodes + NPB - 1) / NPB;       // 1563
    const int blocks  = n_tiles < GRID ? n_tiles : GRID; // 512
    hipLaunchKernelGGL(sparse_layer_pipe, dim3(blocks), dim3(THREADS), 0, stream,
                       self_vecs, neigh_vecs, weight, bias, out, n_nodes);
}

// Round 5
// 178.567 us; speedup vs baseline: 1.0415x; 1.0415x over previous
//
#include <hip/hip_runtime.h>

// SparseLayer: out[n] = ((self[n] + sum_j neigh[n*32+j]) / 33) @ W + bias
// N=50000, NEIGH=32, D=128, fp32.
//
// R5: one node per wave-round, neighbor block read as 16 fully-linear 1-KB
// wave-loads (lane i -> base + l*1KB + i*16B). Halves hold even/odd row
// partial sums; cross-half shfl_xor(32) merge. GEMM k-split across halves,
// merged the same way. One stream per wave, strictly sequential addresses.

typedef float f32x4 __attribute__((ext_vector_type(4)));

constexpr int D       = 128;
constexpr int D4      = D / 4;           // 32
constexpr int NEIGH   = 32;
constexpr int WAVES   = 8;
constexpr int THREADS = WAVES * 64;      // 512
constexpr int NPW     = 4;               // nodes per wave (serial)
constexpr int NPB     = WAVES * NPW;     // 32 nodes per block

__global__ __launch_bounds__(THREADS, 4) // <=128 VGPR, 2 blocks/CU
void sparse_layer_v3(const float* __restrict__ self_vecs,
                     const float* __restrict__ neigh_vecs,
                     const float* __restrict__ weight,
                     const float* __restrict__ bias,
                     float* __restrict__ out, int n_nodes)
{
    __shared__ float w_lds[D * D];        // 64 KiB
    __shared__ float agg_lds[WAVES][D];   // 4 KiB (one row per wave)

    // ---- stage W into LDS (only barrier in the kernel) ----
    {
        const f32x4* w4 = reinterpret_cast<const f32x4*>(weight);
        f32x4*       wp = reinterpret_cast<f32x4*>(w_lds);
        #pragma unroll
        for (int i = 0; i < (D * D / 4) / THREADS; ++i)
            wp[threadIdx.x + i * THREADS] = w4[threadIdx.x + i * THREADS];
    }
    __syncthreads();

    const int wave = threadIdx.x >> 6;
    const int lane = threadIdx.x & 63;
    const int h    = lane >> 5;           // half: even/odd rows, low/high k
    const int c4   = lane & 31;           // float4 column

    const f32x4* s4 = reinterpret_cast<const f32x4*>(self_vecs);
    const f32x4* g4 = reinterpret_cast<const f32x4*>(neigh_vecs);
    const f32x4* wl = reinterpret_cast<const f32x4*>(w_lds);
    f32x4* arow = reinterpret_cast<f32x4*>(agg_lds[wave]);
    const f32x4 bv = reinterpret_cast<const f32x4*>(bias)[c4];
    constexpr float inv = 1.0f / (NEIGH + 1);

    const long base = (long)blockIdx.x * NPB + wave * NPW;  // wave-contiguous 64 KB

    for (int i = 0; i < NPW; ++i) {
        const long n = base + i;
        if (n >= n_nodes) break;          // wave-uniform branch

        // ---- phase 1: 16 linear 1-KB wave-loads over neigh[n] ----
        const f32x4* p = g4 + n * (long)NEIGH * D4;   // 16 KB block
        f32x4 acc = (f32x4)0.0f;
        if (h == 0) acc = s4[n * D4 + c4];            // self row (half-wave)
        #pragma unroll
        for (int l = 0; l < 16; ++l)
            acc += p[l * 64 + lane];      // lane reads row 2l+h, cols 4c4..+3

        // cross-half merge: full column sums in every lane
        f32x4 tot;
        tot.x = acc.x + __shfl_xor(acc.x, 32);
        tot.y = acc.y + __shfl_xor(acc.y, 32);
        tot.z = acc.z + __shfl_xor(acc.z, 32);
        tot.w = acc.w + __shfl_xor(acc.w, 32);
        tot *= inv;
        if (h == 0) arow[c4] = tot;       // intra-wave LDS publish (in-order)

        // ---- phase 2: GEMM, k split across halves ----
        f32x4 o = (f32x4)0.0f;
        #pragma unroll
        for (int k4 = 0; k4 < D4 / 2; ++k4) {
            const int kk = h * (D4 / 2) + k4;
            f32x4 a  = arow[kk];                       // per-half broadcast
            f32x4 w0 = wl[(4 * kk + 0) * D4 + c4];
            f32x4 w1 = wl[(4 * kk + 1) * D4 + c4];
            f32x4 w2 = wl[(4 * kk + 2) * D4 + c4];
            f32x4 w3 = wl[(4 * kk + 3) * D4 + c4];
            o += a.x * w0;  o += a.y * w1;  o += a.z * w2;  o += a.w * w3;
        }
        o.x += __shfl_xor(o.x, 32);
        o.y += __shfl_xor(o.y, 32);
        o.z += __shfl_xor(o.z, 32);
        o.w += __shfl_xor(o.w, 32);
        if (h == 0)
            reinterpret_cast<f32x4*>(out)[n * D4 + c4] = o + bv;
    }
}

extern "C" void kernel_launch(void* const* d_in, const int* in_sizes, int n_in,
                              void* d_out, int out_size, void* d_ws, size_t ws_size,
                              hipStream_t stream) {
    const float* self_vecs  = (const float*)d_in[0];
    const float* neigh_vecs = (const float*)d_in[1];
    // d_in[2] = neigh_num (==32, compile-time NEIGH)
    const float* weight     = (const float*)d_in[3];
    const float* bias       = (const float*)d_in[4];
    float*       out        = (float*)d_out;

    const int n_nodes = in_sizes[0] / D;                 // 50000
    const int blocks  = (n_nodes + NPB - 1) / NPB;       // 1563
    hipLaunchKernelGGL(sparse_layer_v3, dim3(blocks), dim3(THREADS), 0, stream,
                       self_vecs, neigh_vecs, weight, bias, out, n_nodes);
}

// Round 6
// 160.155 us; speedup vs baseline: 1.1613x; 1.1150x over previous
//
#include <hip/hip_runtime.h>

// SparseLayer: out[n] = ((self[n] + sum_j neigh[n*32+j]) / 33) @ W + bias
// N=50000, NEIGH=32, D=128, fp32.
//
// R6 concurrency probe: no W in LDS (W read from L1/L2 during the sweep),
// LDS = 8 KiB agg only, 256-thread blocks, launch_bounds(256,6) -> target
// <=85 VGPR -> up to 24 waves/CU (vs 16 in all prior rounds).
// Per wave: aggregate 4 nodes (phase 1, NT stream), then ONE W sweep from
// global computing all 4 outputs (phase 2, h-split over k). No barriers
// after launch; agg rows are wave-private.

typedef float f32x4 __attribute__((ext_vector_type(4)));

constexpr int D       = 128;
constexpr int D4      = D / 4;            // 32
constexpr int NEIGH   = 32;
constexpr int WAVES   = 4;
constexpr int THREADS = WAVES * 64;       // 256
constexpr int NPW     = 4;                // nodes per wave
constexpr int NPB     = WAVES * NPW;      // 16 nodes per block -> 3125 blocks exact

__global__ __launch_bounds__(THREADS, 6)  // 6 waves/SIMD target (<=85 VGPR)
void sparse_layer_v4(const float* __restrict__ self_vecs,
                     const float* __restrict__ neigh_vecs,
                     const float* __restrict__ weight,
                     const float* __restrict__ bias,
                     float* __restrict__ out, int n_nodes)
{
    __shared__ float agg_lds[WAVES][NPW][D];   // 8 KiB

    const int wave = threadIdx.x >> 6;
    const int lane = threadIdx.x & 63;
    const int h    = lane >> 5;            // half: even/odd rows, low/high k
    const int c4   = lane & 31;            // float4 column

    const f32x4* s4 = reinterpret_cast<const f32x4*>(self_vecs);
    const f32x4* g4 = reinterpret_cast<const f32x4*>(neigh_vecs);
    const f32x4* w4 = reinterpret_cast<const f32x4*>(weight);
    constexpr float inv = 1.0f / (NEIGH + 1);

    const long base = (long)blockIdx.x * NPB + wave * NPW;

    // ---- phase 1: aggregate 4 nodes (16 linear 1-KB wave-loads each) ----
    #pragma unroll
    for (int i = 0; i < NPW; ++i) {
        const long n = base + i;
        if (n >= n_nodes) break;           // wave-uniform (never taken at N=50000)
        const f32x4* p = g4 + n * (long)NEIGH * D4;
        f32x4 acc = (f32x4)0.0f;
        if (h == 0) acc = __builtin_nontemporal_load(&s4[n * D4 + c4]);
        #pragma unroll 8
        for (int l = 0; l < 16; ++l)
            acc += __builtin_nontemporal_load(&p[l * 64 + lane]);  // row 2l+h
        f32x4 tot;
        tot.x = acc.x + __shfl_xor(acc.x, 32);
        tot.y = acc.y + __shfl_xor(acc.y, 32);
        tot.z = acc.z + __shfl_xor(acc.z, 32);
        tot.w = acc.w + __shfl_xor(acc.w, 32);
        if (h == 0)
            reinterpret_cast<f32x4*>(agg_lds[wave][i])[c4] = tot * inv;
    }

    // ---- phase 2: one W sweep (global/L2) computes all 4 nodes ----
    f32x4 o0 = (f32x4)0.0f, o1 = (f32x4)0.0f, o2 = (f32x4)0.0f, o3 = (f32x4)0.0f;
    const f32x4* a0 = reinterpret_cast<const f32x4*>(agg_lds[wave][0]);
    const f32x4* a1 = reinterpret_cast<const f32x4*>(agg_lds[wave][1]);
    const f32x4* a2 = reinterpret_cast<const f32x4*>(agg_lds[wave][2]);
    const f32x4* a3 = reinterpret_cast<const f32x4*>(agg_lds[wave][3]);

    #pragma unroll 4
    for (int k4 = 0; k4 < D4 / 2; ++k4) {
        const int kk = h * (D4 / 2) + k4;         // h-split k range
        f32x4 w0 = w4[(4 * kk + 0) * D4 + c4];    // L1/L2-resident, coalesced
        f32x4 w1 = w4[(4 * kk + 1) * D4 + c4];
        f32x4 w2 = w4[(4 * kk + 2) * D4 + c4];
        f32x4 w3 = w4[(4 * kk + 3) * D4 + c4];
        f32x4 b0 = a0[kk];                        // LDS broadcast within half
        f32x4 b1 = a1[kk];
        f32x4 b2 = a2[kk];
        f32x4 b3 = a3[kk];
        o0 += b0.x * w0;  o0 += b0.y * w1;  o0 += b0.z * w2;  o0 += b0.w * w3;
        o1 += b1.x * w0;  o1 += b1.y * w1;  o1 += b1.z * w2;  o1 += b1.w * w3;
        o2 += b2.x * w0;  o2 += b2.y * w1;  o2 += b2.z * w2;  o2 += b2.w * w3;
        o3 += b3.x * w0;  o3 += b3.y * w1;  o3 += b3.z * w2;  o3 += b3.w * w3;
    }

    // cross-half merge + write
    const f32x4 bv = reinterpret_cast<const f32x4*>(bias)[c4];
    f32x4* o4 = reinterpret_cast<f32x4*>(out);
    f32x4 oo[NPW] = {o0, o1, o2, o3};
    #pragma unroll
    for (int i = 0; i < NPW; ++i) {
        f32x4 o = oo[i];
        o.x += __shfl_xor(o.x, 32);
        o.y += __shfl_xor(o.y, 32);
        o.z += __shfl_xor(o.z, 32);
        o.w += __shfl_xor(o.w, 32);
        const long n = base + i;
        if (h == 0 && n < n_nodes)
            __builtin_nontemporal_store(o + bv, &o4[n * D4 + c4]);
    }
}

extern "C" void kernel_launch(void* const* d_in, const int* in_sizes, int n_in,
                              void* d_out, int out_size, void* d_ws, size_t ws_size,
                              hipStream_t stream) {
    const float* self_vecs  = (const float*)d_in[0];
    const float* neigh_vecs = (const float*)d_in[1];
    // d_in[2] = neigh_num (==32, compile-time NEIGH)
    const float* weight     = (const float*)d_in[3];
    const float* bias       = (const float*)d_in[4];
    float*       out        = (float*)d_out;

    const int n_nodes = in_sizes[0] / D;                 // 50000
    const int blocks  = (n_nodes + NPB - 1) / NPB;       // 3125 exact
    hipLaunchKernelGGL(sparse_layer_v4, dim3(blocks), dim3(THREADS), 0, stream,
                       self_vecs, neigh_vecs, weight, bias, out, n_nodes);
}